// Round 3
// baseline (149.088 us; speedup 1.0000x reference)
//
#include <hip/hip_runtime.h>

// Head: k = x@Wk^T; q = k (source bug); wei = softmax(causal(q k^T / 8)); v = x@Wv^T; out = wei@v
// B=8, T=2048, C=1024, H=64. fp32 in/out, bf16 MFMA internally.
//
// R2 -> R3: occupancy. proj: 1024 blocks (32x64 tiles, 13.8KB LDS -> 4 blocks/CU).
// attn: 4-way KV-split (grid 1024, max 8 iters vs 32, 4 blocks/CU); fixed-max softmax
// makes partial (O, l) additive -> scratch + combine kernel.

typedef __bf16 bf16;
typedef __bf16 bf16x8 __attribute__((ext_vector_type(8)));
typedef float  floatx4 __attribute__((ext_vector_type(4)));

#define T_LEN 2048
#define HEAD  64
#define CEMB  1024

static __device__ __forceinline__ bf16x8 cvt2(float4 a, float4 b) {
    bf16x8 r;
    r[0] = (bf16)a.x; r[1] = (bf16)a.y; r[2] = (bf16)a.z; r[3] = (bf16)a.w;
    r[4] = (bf16)b.x; r[5] = (bf16)b.y; r[6] = (bf16)b.z; r[7] = (bf16)b.w;
    return r;
}

// ---------------- Kernel 1: projection GEMM (W conversion fused).
// Tile: 32 rows x 64 cols, BK=64. blockIdx: mblk = bx>>1 (512), nhalf = bx&1.
// nhalf=0 -> Wk rows -> Kbuf[b][t][h]; nhalf=1 -> Wv rows -> Vt[b][h][t] (transposed).
__global__ __launch_bounds__(256) void proj_kernel(const float* __restrict__ x,
                                                   const float* __restrict__ Wk,
                                                   const float* __restrict__ Wv,
                                                   bf16* __restrict__ Kbuf,
                                                   bf16* __restrict__ Vt) {
    __shared__ __align__(16) bf16 As[32][72];
    __shared__ __align__(16) bf16 Bs[64][72];

    const int tid  = threadIdx.x;
    const int wave = tid >> 6;
    const int lane = tid & 63;
    const int quad = lane >> 4;
    const int low  = lane & 15;

    const int mblk  = blockIdx.x >> 1;
    const int nhalf = blockIdx.x & 1;
    const long row0 = (long)mblk * 32;

    // staging maps (BK=64)
    const int a_row = tid >> 3;          // 0..31, 8 fp32 per thread
    const int a_col = (tid & 7) * 8;
    const int b_row = tid >> 2;          // 0..63, 16 fp32 per thread
    const int b_col = (tid & 3) * 16;

    const float* abase = x + (row0 + a_row) * CEMB + a_col;
    const float* wrow  = (nhalf ? Wv : Wk) + b_row * CEMB + b_col;

    const int strip = wave & 1;          // M strip (16 rows)
    const int npair = wave >> 1;         // 2 n-tiles per wave

    floatx4 acc[2];
    acc[0] = (floatx4){0.f, 0.f, 0.f, 0.f};
    acc[1] = (floatx4){0.f, 0.f, 0.f, 0.f};

    // prologue prefetch
    float4 apf[2], bpf[4];
#pragma unroll
    for (int i = 0; i < 2; ++i) apf[i] = ((const float4*)abase)[i];
#pragma unroll
    for (int i = 0; i < 4; ++i) bpf[i] = ((const float4*)wrow)[i];

    for (int s = 0; s < 16; ++s) {
        __syncthreads();
        *(bf16x8*)&As[a_row][a_col] = cvt2(apf[0], apf[1]);
        *(bf16x8*)&Bs[b_row][b_col]     = cvt2(bpf[0], bpf[1]);
        *(bf16x8*)&Bs[b_row][b_col + 8] = cvt2(bpf[2], bpf[3]);
        if (s < 15) {
            const int k0 = (s + 1) * 64;
#pragma unroll
            for (int i = 0; i < 2; ++i) apf[i] = ((const float4*)(abase + k0))[i];
#pragma unroll
            for (int i = 0; i < 4; ++i) bpf[i] = ((const float4*)(wrow + k0))[i];
        }
        __syncthreads();

#pragma unroll
        for (int h = 0; h < 2; ++h) {
            bf16x8 afrag = *(const bf16x8*)&As[strip * 16 + low][h * 32 + quad * 8];
#pragma unroll
            for (int i = 0; i < 2; ++i) {
                bf16x8 bfrag = *(const bf16x8*)&Bs[(npair * 2 + i) * 16 + low][h * 32 + quad * 8];
                acc[i] = __builtin_amdgcn_mfma_f32_16x16x32_bf16(afrag, bfrag, acc[i], 0, 0, 0);
            }
        }
    }

    // epilogue
#pragma unroll
    for (int i = 0; i < 2; ++i) {
#pragma unroll
        for (int r = 0; r < 4; ++r) {
            long trow = row0 + strip * 16 + quad * 4 + r;
            long b    = trow >> 11;
            int  tloc = (int)(trow & 2047);
            int  cl   = (npair * 2 + i) * 16 + low;   // 0..63
            bf16 val  = (bf16)acc[i][r];
            if (nhalf == 0) Kbuf[(b * T_LEN + tloc) * HEAD + cl] = val;
            else            Vt[(b * HEAD + cl) * T_LEN + tloc]   = val;
        }
    }
}

// ---------------- Kernel 2: attention partial. q=k, causal, scale 1/8, fixed-max softmax.
// blockIdx.x = ((b*32 + qb)*4 + c); chunk c handles kv tiles j in {c, c+4, ...} <= qb.
// Writes Opart[block][64][64] fp32 and lpart[block][64] fp32 (zeros if no work).
__global__ __launch_bounds__(256) void attn_kernel(const bf16* __restrict__ Kbuf,
                                                   const bf16* __restrict__ Vt,
                                                   float* __restrict__ Opart,
                                                   float* __restrict__ lpart) {
    __shared__ __align__(16) bf16 Qs[64][72];
    __shared__ __align__(16) bf16 Ks[64][72];
    __shared__ __align__(16) bf16 Vs[64][72];   // [h][kv]
    __shared__ __align__(16) bf16 Ps[64][72];

    const int tid  = threadIdx.x;
    const int wave = tid >> 6;
    const int lane = tid & 63;
    const int quad = lane >> 4;
    const int low  = lane & 15;

    const int c  = blockIdx.x & 3;
    const int qb = (blockIdx.x >> 2) & 31;
    const int b  = blockIdx.x >> 7;

    const bf16* kbase = Kbuf + (long)b * T_LEN * HEAD;
    const bf16* vbase = Vt + (long)b * HEAD * T_LEN;

    const int s_row = tid >> 2;          // 0..63
    const int s_col = (tid & 3) * 16;    // bf16 cols

    // stage Q tile (= K rows, since q = k)
    {
        const bf16* src = kbase + (qb * 64 + s_row) * HEAD + s_col;
        *(float4*)&Qs[s_row][s_col]     = *(const float4*)(src);
        *(float4*)&Qs[s_row][s_col + 8] = *(const float4*)(src + 8);
    }
    __syncthreads();
    const bf16x8 qf0 = *(const bf16x8*)&Qs[wave * 16 + low][quad * 8];
    const bf16x8 qf1 = *(const bf16x8*)&Qs[wave * 16 + low][32 + quad * 8];

    bf16x8 ones;
#pragma unroll
    for (int i = 0; i < 8; ++i) ones[i] = (bf16)1.0f;

    floatx4 o[4], ol;
#pragma unroll
    for (int nt = 0; nt < 4; ++nt) o[nt] = (floatx4){0.f, 0.f, 0.f, 0.f};
    ol = (floatx4){0.f, 0.f, 0.f, 0.f};

    const bf16* ksrc = kbase + s_row * HEAD + s_col;
    const bf16* vsrc = vbase + (long)s_row * T_LEN + s_col;

    if (c <= qb) {
        // prologue prefetch tile j=c
        float4 kpf0 = *(const float4*)(ksrc + c * 4096);
        float4 kpf1 = *(const float4*)(ksrc + c * 4096 + 8);
        float4 vpf0 = *(const float4*)(vsrc + c * 64);
        float4 vpf1 = *(const float4*)(vsrc + c * 64 + 8);

        for (int j = c; j <= qb; j += 4) {
            __syncthreads();
            *(float4*)&Ks[s_row][s_col]     = kpf0;
            *(float4*)&Ks[s_row][s_col + 8] = kpf1;
            *(float4*)&Vs[s_row][s_col]     = vpf0;
            *(float4*)&Vs[s_row][s_col + 8] = vpf1;
            if (j + 4 <= qb) {
                kpf0 = *(const float4*)(ksrc + (j + 4) * 4096);
                kpf1 = *(const float4*)(ksrc + (j + 4) * 4096 + 8);
                vpf0 = *(const float4*)(vsrc + (j + 4) * 64);
                vpf1 = *(const float4*)(vsrc + (j + 4) * 64 + 8);
            }
            __syncthreads();

            // S = Q K^T
            floatx4 s_[4];
#pragma unroll
            for (int nt = 0; nt < 4; ++nt) {
                bf16x8 kf0 = *(const bf16x8*)&Ks[nt * 16 + low][quad * 8];
                bf16x8 kf1 = *(const bf16x8*)&Ks[nt * 16 + low][32 + quad * 8];
                floatx4 z = (floatx4){0.f, 0.f, 0.f, 0.f};
                z = __builtin_amdgcn_mfma_f32_16x16x32_bf16(qf0, kf0, z, 0, 0, 0);
                z = __builtin_amdgcn_mfma_f32_16x16x32_bf16(qf1, kf1, z, 0, 0, 0);
                s_[nt] = z;
            }

            // p = exp2(s * 0.125*log2e); causal mask on diagonal tile; P strip -> LDS
            const bool diag = (j == qb);
#pragma unroll
            for (int nt = 0; nt < 4; ++nt) {
#pragma unroll
                for (int r = 0; r < 4; ++r) {
                    float p = __builtin_amdgcn_exp2f(s_[nt][r] * 0.180336880f);
                    if (diag && (nt * 16 + low) > (wave * 16 + quad * 4 + r)) p = 0.f;
                    Ps[wave * 16 + quad * 4 + r][nt * 16 + low] = (bf16)p;
                }
            }

            // O += P V ; l += P . ones
            bf16x8 pf0 = *(const bf16x8*)&Ps[wave * 16 + low][quad * 8];
            bf16x8 pf1 = *(const bf16x8*)&Ps[wave * 16 + low][32 + quad * 8];
#pragma unroll
            for (int nt = 0; nt < 4; ++nt) {
                bf16x8 vf0 = *(const bf16x8*)&Vs[nt * 16 + low][quad * 8];
                bf16x8 vf1 = *(const bf16x8*)&Vs[nt * 16 + low][32 + quad * 8];
                o[nt] = __builtin_amdgcn_mfma_f32_16x16x32_bf16(pf0, vf0, o[nt], 0, 0, 0);
                o[nt] = __builtin_amdgcn_mfma_f32_16x16x32_bf16(pf1, vf1, o[nt], 0, 0, 0);
            }
            ol = __builtin_amdgcn_mfma_f32_16x16x32_bf16(pf0, ones, ol, 0, 0, 0);
            ol = __builtin_amdgcn_mfma_f32_16x16x32_bf16(pf1, ones, ol, 0, 0, 0);
        }
    }

    // write partials (zeros if no work) — Opart[block][row][h], lpart[block][row]
    float* ob = Opart + (long)blockIdx.x * 4096;
#pragma unroll
    for (int nt = 0; nt < 4; ++nt) {
#pragma unroll
        for (int r = 0; r < 4; ++r) {
            int row = wave * 16 + quad * 4 + r;
            ob[row * 64 + nt * 16 + low] = o[nt][r];
        }
    }
    if (low == 0) {
#pragma unroll
        for (int r = 0; r < 4; ++r)
            lpart[(long)blockIdx.x * 64 + wave * 16 + quad * 4 + r] = ol[r];
    }
}

// ---------------- Kernel 3: combine. out[tile] = sum_c Opart / sum_c lpart.
// blockIdx.x = tile (b*32+qb), 256 threads; thread handles 16 elems of one row.
__global__ __launch_bounds__(256) void attn_combine(const float* __restrict__ Opart,
                                                    const float* __restrict__ lpart,
                                                    float* __restrict__ out) {
    const int tile = blockIdx.x;
    const int tid  = threadIdx.x;
    const int row  = tid >> 2;           // 0..63
    const int col0 = (tid & 3) * 16;

    const float* ob = Opart + (long)tile * 4 * 4096 + row * 64 + col0;
    const float* lb = lpart + (long)tile * 4 * 64 + row;

    float l = lb[0] + lb[64] + lb[128] + lb[192];
    float rl = 1.0f / l;

    float4 s0 = (float4){0.f, 0.f, 0.f, 0.f}, s1 = s0, s2 = s0, s3 = s0;
#pragma unroll
    for (int ch = 0; ch < 4; ++ch) {
        const float4* p = (const float4*)(ob + ch * 4096);
        float4 a = p[0], b = p[1], c = p[2], d = p[3];
        s0.x += a.x; s0.y += a.y; s0.z += a.z; s0.w += a.w;
        s1.x += b.x; s1.y += b.y; s1.z += b.z; s1.w += b.w;
        s2.x += c.x; s2.y += c.y; s2.z += c.z; s2.w += c.w;
        s3.x += d.x; s3.y += d.y; s3.z += d.z; s3.w += d.w;
    }
    s0.x *= rl; s0.y *= rl; s0.z *= rl; s0.w *= rl;
    s1.x *= rl; s1.y *= rl; s1.z *= rl; s1.w *= rl;
    s2.x *= rl; s2.y *= rl; s2.z *= rl; s2.w *= rl;
    s3.x *= rl; s3.y *= rl; s3.z *= rl; s3.w *= rl;

    float4* op = (float4*)(out + (long)tile * 4096 + row * 64 + col0);
    op[0] = s0; op[1] = s1; op[2] = s2; op[3] = s3;
}

extern "C" void kernel_launch(void* const* d_in, const int* in_sizes, int n_in,
                              void* d_out, int out_size, void* d_ws, size_t ws_size,
                              hipStream_t stream) {
    const float* x  = (const float*)d_in[0];
    const float* Wk = (const float*)d_in[1];
    const float* Wv = (const float*)d_in[2];
    float* out = (float*)d_out;

    char* ws = (char*)d_ws;
    bf16*  Kbuf  = (bf16*)ws;                           // 2 MB
    bf16*  Vt    = (bf16*)(ws + (2 << 20));             // 2 MB
    float* Opart = (float*)(ws + (4 << 20));            // 1024*4096*4 = 16 MB
    float* lpart = (float*)(ws + (20 << 20));           // 1024*64*4   = 256 KB

    proj_kernel<<<1024, 256, 0, stream>>>(x, Wk, Wv, Kbuf, Vt);
    attn_kernel<<<1024, 256, 0, stream>>>(Kbuf, Vt, Opart, lpart);
    attn_combine<<<256, 256, 0, stream>>>(Opart, lpart, out);
}

// Round 4
// 145.244 us; speedup vs baseline: 1.0265x; 1.0265x over previous
//
#include <hip/hip_runtime.h>

// Head: k = x@Wk^T; q = k (source bug); wei = softmax(causal(q k^T / 8)); v = x@Wv^T; out = wei@v
// B=8, T=2048, C=1024, H=64. fp32 in/out, bf16 MFMA internally.
//
// R3 -> R4: (1) W pre-converted to bf16 (wconv) - halves W bytes; (2) single-barrier
// double-buffered K-loops (vmcnt drain behind compute, 1 barrier/iter); (3) proj grid 512,
// 32x128 full-N tiles (half the W re-reads of R3); (4) attn 8-way KV split, Q frags direct
// from global, K/V double-buffered.

typedef __bf16 bf16;
typedef __bf16 bf16x4 __attribute__((ext_vector_type(4)));
typedef __bf16 bf16x8 __attribute__((ext_vector_type(8)));
typedef float  floatx4 __attribute__((ext_vector_type(4)));

#define T_LEN 2048
#define HEAD  64
#define CEMB  1024

static __device__ __forceinline__ bf16x8 cvt2(float4 a, float4 b) {
    bf16x8 r;
    r[0] = (bf16)a.x; r[1] = (bf16)a.y; r[2] = (bf16)a.z; r[3] = (bf16)a.w;
    r[4] = (bf16)b.x; r[5] = (bf16)b.y; r[6] = (bf16)b.z; r[7] = (bf16)b.w;
    return r;
}

// ---------------- Kernel 0: W fp32 -> bf16, [Wk;Wv] concat as Wb[128][1024]
__global__ __launch_bounds__(256) void wconv_kernel(const float* __restrict__ Wk,
                                                    const float* __restrict__ Wv,
                                                    bf16* __restrict__ Wb) {
    int i = (blockIdx.x * 256 + threadIdx.x) * 4;   // grid 128 covers 131072
    const float* src = (i < 64 * 1024) ? (Wk + i) : (Wv + (i - 64 * 1024));
    float4 f = *(const float4*)src;
    bf16x4 v;
    v[0] = (bf16)f.x; v[1] = (bf16)f.y; v[2] = (bf16)f.z; v[3] = (bf16)f.w;
    *(bf16x4*)&Wb[i] = v;
}

// ---------------- Kernel 1: projection GEMM. grid 512, tile 32 rows x 128 cols, BK=64.
// Double-buffered LDS, one barrier per K-step.
__global__ __launch_bounds__(256) void proj_kernel(const float* __restrict__ x,
                                                   const bf16* __restrict__ Wb,
                                                   bf16* __restrict__ Kbuf,
                                                   bf16* __restrict__ Vt) {
    __shared__ __align__(16) bf16 As[2][32][72];
    __shared__ __align__(16) bf16 Bs[2][128][72];

    const int tid  = threadIdx.x;
    const int wave = tid >> 6;
    const int lane = tid & 63;
    const int quad = lane >> 4;
    const int low  = lane & 15;

    const long row0 = (long)blockIdx.x * 32;

    const int a_row = tid >> 3;          // 0..31, 8 fp32/thread
    const int a_col = (tid & 7) * 8;
    const int b_row = tid >> 1;          // 0..127, 32 bf16/thread
    const int b_col = (tid & 1) * 32;

    const float* abase = x + (row0 + a_row) * CEMB + a_col;
    const bf16*  bbase = Wb + b_row * CEMB + b_col;

    const int strip = wave & 1;          // 16-row M strip
    const int nq    = (wave >> 1) * 4;   // first of 4 n-tiles

    floatx4 acc[4];
#pragma unroll
    for (int i = 0; i < 4; ++i) acc[i] = (floatx4){0.f, 0.f, 0.f, 0.f};

    // prologue: stage step 0 into buf 0
    float4 apf0 = ((const float4*)abase)[0], apf1 = ((const float4*)abase)[1];
    float4 bpf0 = ((const float4*)bbase)[0], bpf1 = ((const float4*)bbase)[1];
    float4 bpf2 = ((const float4*)bbase)[2], bpf3 = ((const float4*)bbase)[3];
    *(bf16x8*)&As[0][a_row][a_col] = cvt2(apf0, apf1);
    *(float4*)&Bs[0][b_row][b_col]      = bpf0;
    *(float4*)&Bs[0][b_row][b_col + 8]  = bpf1;
    *(float4*)&Bs[0][b_row][b_col + 16] = bpf2;
    *(float4*)&Bs[0][b_row][b_col + 24] = bpf3;
    __syncthreads();

    int buf = 0;
    for (int s = 0; s < 16; ++s) {
        const bool more = (s < 15);
        if (more) {   // issue prefetch for s+1 (in flight during MFMAs)
            const int k0 = (s + 1) * 64;
            apf0 = ((const float4*)(abase + k0))[0]; apf1 = ((const float4*)(abase + k0))[1];
            bpf0 = ((const float4*)(bbase + k0))[0]; bpf1 = ((const float4*)(bbase + k0))[1];
            bpf2 = ((const float4*)(bbase + k0))[2]; bpf3 = ((const float4*)(bbase + k0))[3];
        }
#pragma unroll
        for (int ks = 0; ks < 2; ++ks) {
            bf16x8 afrag = *(const bf16x8*)&As[buf][strip * 16 + low][ks * 32 + quad * 8];
#pragma unroll
            for (int i = 0; i < 4; ++i) {
                bf16x8 bfrag = *(const bf16x8*)&Bs[buf][(nq + i) * 16 + low][ks * 32 + quad * 8];
                acc[i] = __builtin_amdgcn_mfma_f32_16x16x32_bf16(afrag, bfrag, acc[i], 0, 0, 0);
            }
        }
        if (more) {   // store prefetch to alternate buffer, then the single barrier
            const int nb = buf ^ 1;
            *(bf16x8*)&As[nb][a_row][a_col] = cvt2(apf0, apf1);
            *(float4*)&Bs[nb][b_row][b_col]      = bpf0;
            *(float4*)&Bs[nb][b_row][b_col + 8]  = bpf1;
            *(float4*)&Bs[nb][b_row][b_col + 16] = bpf2;
            *(float4*)&Bs[nb][b_row][b_col + 24] = bpf3;
            __syncthreads();
            buf = nb;
        }
    }

    // epilogue: C-layout col=(nq+i)*16+low, row=strip*16+quad*4+r
    const long bidx  = row0 >> 11;
    const int  tloc0 = (int)(row0 & 2047);
#pragma unroll
    for (int i = 0; i < 4; ++i) {
#pragma unroll
        for (int r = 0; r < 4; ++r) {
            int trow = tloc0 + strip * 16 + quad * 4 + r;
            int cl   = (nq + i) * 16 + low;
            bf16 val = (bf16)acc[i][r];
            if (cl < HEAD) Kbuf[(bidx * T_LEN + trow) * HEAD + cl] = val;
            else           Vt[(bidx * HEAD + (cl - HEAD)) * T_LEN + trow] = val;
        }
    }
}

// ---------------- Kernel 2: attention partial. q=k, causal, scale 1/8, fixed-max softmax.
// blockIdx.x = ((b*32 + qb)*8 + c); chunk c: kv tiles j in {c, c+8, ...} <= qb.
// K/V double-buffered (1 barrier/iter); Q frags loaded directly from global.
__global__ __launch_bounds__(256) void attn_kernel(const bf16* __restrict__ Kbuf,
                                                   const bf16* __restrict__ Vt,
                                                   float* __restrict__ Opart,
                                                   float* __restrict__ lpart) {
    __shared__ __align__(16) bf16 Ks[2][64][72];
    __shared__ __align__(16) bf16 Vs[2][64][72];   // [h][kv]
    __shared__ __align__(16) bf16 Ps[64][72];

    const int tid  = threadIdx.x;
    const int wave = tid >> 6;
    const int lane = tid & 63;
    const int quad = lane >> 4;
    const int low  = lane & 15;

    const int c  = blockIdx.x & 7;
    const int qb = (blockIdx.x >> 3) & 31;
    const int b  = blockIdx.x >> 8;

    const bf16* kbase = Kbuf + (long)b * T_LEN * HEAD;
    const bf16* vbase = Vt + (long)b * HEAD * T_LEN;

    // Q fragments (A-layout) straight from global: row qb*64+wave*16+low, k = quad*8..+7 (+32)
    const bf16* qrow = kbase + (qb * 64 + wave * 16 + low) * HEAD + quad * 8;
    const bf16x8 qf0 = *(const bf16x8*)(qrow);
    const bf16x8 qf1 = *(const bf16x8*)(qrow + 32);

    bf16x8 ones;
#pragma unroll
    for (int i = 0; i < 8; ++i) ones[i] = (bf16)1.0f;

    floatx4 o[4], ol;
#pragma unroll
    for (int nt = 0; nt < 4; ++nt) o[nt] = (floatx4){0.f, 0.f, 0.f, 0.f};
    ol = (floatx4){0.f, 0.f, 0.f, 0.f};

    const int s_row = tid >> 2;          // 0..63
    const int s_col = (tid & 3) * 16;
    const bf16* ksrc = kbase + s_row * HEAD + s_col;
    const bf16* vsrc = vbase + (long)s_row * T_LEN + s_col;

    if (c <= qb) {
        // prologue: stage tile j=c into buf 0
        float4 kpf0 = *(const float4*)(ksrc + c * 4096);
        float4 kpf1 = *(const float4*)(ksrc + c * 4096 + 8);
        float4 vpf0 = *(const float4*)(vsrc + c * 64);
        float4 vpf1 = *(const float4*)(vsrc + c * 64 + 8);
        *(float4*)&Ks[0][s_row][s_col]     = kpf0;
        *(float4*)&Ks[0][s_row][s_col + 8] = kpf1;
        *(float4*)&Vs[0][s_row][s_col]     = vpf0;
        *(float4*)&Vs[0][s_row][s_col + 8] = vpf1;
        __syncthreads();

        int buf = 0;
        for (int j = c; j <= qb; j += 8) {
            const bool more = (j + 8 <= qb);
            if (more) {   // prefetch next tile (in flight during compute)
                kpf0 = *(const float4*)(ksrc + (j + 8) * 4096);
                kpf1 = *(const float4*)(ksrc + (j + 8) * 4096 + 8);
                vpf0 = *(const float4*)(vsrc + (j + 8) * 64);
                vpf1 = *(const float4*)(vsrc + (j + 8) * 64 + 8);
            }

            // S = Q K^T ; per-wave S tile [16 x 64]
            floatx4 s_[4];
#pragma unroll
            for (int nt = 0; nt < 4; ++nt) {
                bf16x8 kf0 = *(const bf16x8*)&Ks[buf][nt * 16 + low][quad * 8];
                bf16x8 kf1 = *(const bf16x8*)&Ks[buf][nt * 16 + low][32 + quad * 8];
                floatx4 z = (floatx4){0.f, 0.f, 0.f, 0.f};
                z = __builtin_amdgcn_mfma_f32_16x16x32_bf16(qf0, kf0, z, 0, 0, 0);
                z = __builtin_amdgcn_mfma_f32_16x16x32_bf16(qf1, kf1, z, 0, 0, 0);
                s_[nt] = z;
            }

            // p = exp2(s * 0.125*log2e); causal mask on diagonal tile; P strip -> LDS
            const bool diag = (j == qb);
#pragma unroll
            for (int nt = 0; nt < 4; ++nt) {
#pragma unroll
                for (int r = 0; r < 4; ++r) {
                    float p = __builtin_amdgcn_exp2f(s_[nt][r] * 0.180336880f);
                    if (diag && (nt * 16 + low) > (wave * 16 + quad * 4 + r)) p = 0.f;
                    Ps[wave * 16 + quad * 4 + r][nt * 16 + low] = (bf16)p;
                }
            }

            // O += P V ; l += P . ones  (Ps rows are wave-private: no barrier needed)
            bf16x8 pf0 = *(const bf16x8*)&Ps[wave * 16 + low][quad * 8];
            bf16x8 pf1 = *(const bf16x8*)&Ps[wave * 16 + low][32 + quad * 8];
#pragma unroll
            for (int nt = 0; nt < 4; ++nt) {
                bf16x8 vf0 = *(const bf16x8*)&Vs[buf][nt * 16 + low][quad * 8];
                bf16x8 vf1 = *(const bf16x8*)&Vs[buf][nt * 16 + low][32 + quad * 8];
                o[nt] = __builtin_amdgcn_mfma_f32_16x16x32_bf16(pf0, vf0, o[nt], 0, 0, 0);
                o[nt] = __builtin_amdgcn_mfma_f32_16x16x32_bf16(pf1, vf1, o[nt], 0, 0, 0);
            }
            ol = __builtin_amdgcn_mfma_f32_16x16x32_bf16(pf0, ones, ol, 0, 0, 0);
            ol = __builtin_amdgcn_mfma_f32_16x16x32_bf16(pf1, ones, ol, 0, 0, 0);

            if (more) {   // store prefetch to alternate buffer; single barrier
                const int nb = buf ^ 1;
                *(float4*)&Ks[nb][s_row][s_col]     = kpf0;
                *(float4*)&Ks[nb][s_row][s_col + 8] = kpf1;
                *(float4*)&Vs[nb][s_row][s_col]     = vpf0;
                *(float4*)&Vs[nb][s_row][s_col + 8] = vpf1;
                __syncthreads();
                buf = nb;
            }
        }
    }

    // write partials (zeros if no work)
    float* ob = Opart + (long)blockIdx.x * 4096;
#pragma unroll
    for (int nt = 0; nt < 4; ++nt) {
#pragma unroll
        for (int r = 0; r < 4; ++r) {
            int row = wave * 16 + quad * 4 + r;
            ob[row * 64 + nt * 16 + low] = o[nt][r];
        }
    }
    if (low == 0) {
#pragma unroll
        for (int r = 0; r < 4; ++r)
            lpart[(long)blockIdx.x * 64 + wave * 16 + quad * 4 + r] = ol[r];
    }
}

// ---------------- Kernel 3: combine 8 chunks. out = sum_c Opart / sum_c lpart.
__global__ __launch_bounds__(256) void attn_combine(const float* __restrict__ Opart,
                                                    const float* __restrict__ lpart,
                                                    float* __restrict__ out) {
    const int tile = blockIdx.x;         // 256 = b*32+qb
    const int tid  = threadIdx.x;
    const int row  = tid >> 2;           // 0..63
    const int col0 = (tid & 3) * 16;

    const float* ob = Opart + (long)tile * 8 * 4096 + row * 64 + col0;
    const float* lb = lpart + (long)tile * 8 * 64 + row;

    float l = 0.f;
#pragma unroll
    for (int ch = 0; ch < 8; ++ch) l += lb[ch * 64];
    float rl = 1.0f / l;

    float4 s0 = (float4){0.f, 0.f, 0.f, 0.f}, s1 = s0, s2 = s0, s3 = s0;
#pragma unroll
    for (int ch = 0; ch < 8; ++ch) {
        const float4* p = (const float4*)(ob + ch * 4096);
        float4 a = p[0], b = p[1], c = p[2], d = p[3];
        s0.x += a.x; s0.y += a.y; s0.z += a.z; s0.w += a.w;
        s1.x += b.x; s1.y += b.y; s1.z += b.z; s1.w += b.w;
        s2.x += c.x; s2.y += c.y; s2.z += c.z; s2.w += c.w;
        s3.x += d.x; s3.y += d.y; s3.z += d.z; s3.w += d.w;
    }
    s0.x *= rl; s0.y *= rl; s0.z *= rl; s0.w *= rl;
    s1.x *= rl; s1.y *= rl; s1.z *= rl; s1.w *= rl;
    s2.x *= rl; s2.y *= rl; s2.z *= rl; s2.w *= rl;
    s3.x *= rl; s3.y *= rl; s3.z *= rl; s3.w *= rl;

    float4* op = (float4*)(out + (long)tile * 4096 + row * 64 + col0);
    op[0] = s0; op[1] = s1; op[2] = s2; op[3] = s3;
}

extern "C" void kernel_launch(void* const* d_in, const int* in_sizes, int n_in,
                              void* d_out, int out_size, void* d_ws, size_t ws_size,
                              hipStream_t stream) {
    const float* x  = (const float*)d_in[0];
    const float* Wk = (const float*)d_in[1];
    const float* Wv = (const float*)d_in[2];
    float* out = (float*)d_out;

    char* ws = (char*)d_ws;
    bf16*  Wb    = (bf16*)ws;                           // 256 KB
    bf16*  Kbuf  = (bf16*)(ws + (1 << 20));             // 2 MB
    bf16*  Vt    = (bf16*)(ws + (3 << 20));             // 2 MB
    float* Opart = (float*)(ws + (5 << 20));            // 2048*4096*4 = 32 MB
    float* lpart = (float*)(ws + (37 << 20));           // 512 KB

    wconv_kernel<<<128, 256, 0, stream>>>(Wk, Wv, Wb);
    proj_kernel<<<512, 256, 0, stream>>>(x, Wb, Kbuf, Vt);
    attn_kernel<<<2048, 256, 0, stream>>>(Kbuf, Vt, Opart, lpart);
    attn_combine<<<256, 256, 0, stream>>>(Opart, lpart, out);
}